// Round 1
// baseline (310.758 us; speedup 1.0000x reference)
//
#include <hip/hip_runtime.h>
#include <hip/hip_bf16.h>

// InfiniteNeuralNetwork: the scan state stays row-constant, so
//   p[j] = (1/D) * prod_{d,k} cos^2(inf_w[d,j,k])
// and each infinite layer is just tanh(x @ cls_w + cls_b + p).
// Network = 6 GEMMs [2048x2048x2048] with fused epilogues.

#define DD 2048
#define DEPTH 9

#define BM 128
#define BN 128
#define BK 32

typedef __attribute__((ext_vector_type(8))) short short8;
typedef __attribute__((ext_vector_type(4))) float f32x4;

__device__ __forceinline__ unsigned short f2bf(float f) {
  unsigned u = __float_as_uint(f);
  u += 0x7FFFu + ((u >> 16) & 1u);   // round-to-nearest-even
  return (unsigned short)(u >> 16);
}

// ---------------- prep kernels ----------------

__global__ void cvt_bf16_kernel(const float* __restrict__ s,
                                unsigned short* __restrict__ d, int n4) {
  int i = blockIdx.x * 256 + threadIdx.x;
  if (i >= n4) return;
  float4 v = reinterpret_cast<const float4*>(s)[i];
  ushort4 o;
  o.x = f2bf(v.x); o.y = f2bf(v.y); o.z = f2bf(v.z); o.w = f2bf(v.w);
  reinterpret_cast<ushort4*>(d)[i] = o;
}

// dst[n*D + k] = bf16(src[k*D + n])   (weight [K][N] -> [N][K] bf16)
__global__ void transpose_cvt_kernel(const float* __restrict__ src,
                                     unsigned short* __restrict__ dst) {
  __shared__ float tile[32][33];
  int bx = blockIdx.x * 32;  // n base
  int by = blockIdx.y * 32;  // k base
  int tx = threadIdx.x, ty = threadIdx.y;
#pragma unroll
  for (int i = ty; i < 32; i += 8)
    tile[i][tx] = src[(size_t)(by + i) * DD + bx + tx];
  __syncthreads();
#pragma unroll
  for (int i = ty; i < 32; i += 8)
    dst[(size_t)(bx + i) * DD + by + tx] = f2bf(tile[tx][i]);
}

// padd[j] = cls_b[j] + (1/D) * prod_{d,k} cos^2(inf_w[d,j,k])
__global__ void padd_kernel(const float* __restrict__ inf_w,
                            const float* __restrict__ cls_b,
                            float* __restrict__ padd) {
  int j = blockIdx.x * 256 + threadIdx.x;
  if (j >= DD) return;
  float prod = 1.0f;
#pragma unroll
  for (int d = 0; d < DEPTH; ++d) {
    const float* row = inf_w + ((size_t)d * DD + j) * DD;
    prod *= cosf(row[0]) * cosf(row[1]) * cosf(row[2]);
  }
  padd[j] = cls_b[j] + prod * prod * (1.0f / (float)DD);
}

// ---------------- GEMM (m97 structure) ----------------

__device__ __forceinline__ void gload_lds16(const unsigned short* g,
                                            unsigned short* l) {
  __builtin_amdgcn_global_load_lds(
      (const __attribute__((address_space(1))) void*)g,
      (__attribute__((address_space(3))) void*)l, 16, 0, 0);
}

// EPI: 0 = relu -> bf16, 1 = tanh -> bf16, 2 = relu -> f32
// A: [M][K] bf16 row-major. Bt: [N][K] bf16 (transposed weight). bias: [N] f32.
template <int EPI>
__global__ __launch_bounds__(256) void gemm_kernel(
    const unsigned short* __restrict__ A, const unsigned short* __restrict__ Bt,
    const float* __restrict__ bias, unsigned short* __restrict__ Cb,
    float* __restrict__ Cf) {
  const int N = DD, K = DD;
  __shared__ unsigned short As[BM * BK];  // [128][32]
  __shared__ unsigned short Bs[BN * BK];  // [128][32]

  int tid = threadIdx.x;
  int wid = tid >> 6, lane = tid & 63;
  int wr = wid >> 1, wc = wid & 1;   // wave grid 2x2, each wave 64x64
  int lr = lane & 15;
  int lg = lane >> 4;
  int lk = lg * 8;

  // XCD-aware swizzle: 256 blocks, 8 XCDs, 32 blocks each (bijective).
  int bid = blockIdx.x;
  int swz = (bid & 7) * 32 + (bid >> 3);
  int bcol = (swz & 15) * BN;
  int brow = (swz >> 4) * BM;

  f32x4 acc[4][4];
#pragma unroll
  for (int i = 0; i < 4; ++i)
#pragma unroll
    for (int j = 0; j < 4; ++j) acc[i][j] = f32x4{0.f, 0.f, 0.f, 0.f};

  for (int kt = 0; kt < K; kt += BK) {
    // stage A and Bt tiles (each 128 rows x 32 k, 8KB) via global_load_lds x16B
#pragma unroll
    for (int r = 0; r < 2; ++r) {
      int chunk = r * 256 + tid;          // 512 chunks of 16B per tile
      int row = chunk >> 2;               // 4 chunks per 64B row
      int kof = (chunk & 3) * 8;
      unsigned short* ldsbase_a = &As[(size_t)(r * 256 + wid * 64) * 8];
      unsigned short* ldsbase_b = &Bs[(size_t)(r * 256 + wid * 64) * 8];
      gload_lds16(A + (size_t)(brow + row) * K + kt + kof, ldsbase_a);
      gload_lds16(Bt + (size_t)(bcol + row) * K + kt + kof, ldsbase_b);
    }
    __syncthreads();

    short8 a[4], b[4];
#pragma unroll
    for (int mt = 0; mt < 4; ++mt)
      a[mt] = *reinterpret_cast<const short8*>(&As[(wr * 64 + mt * 16 + lr) * BK + lk]);
#pragma unroll
    for (int nt = 0; nt < 4; ++nt)
      b[nt] = *reinterpret_cast<const short8*>(&Bs[(wc * 64 + nt * 16 + lr) * BK + lk]);
#pragma unroll
    for (int mt = 0; mt < 4; ++mt)
#pragma unroll
      for (int nt = 0; nt < 4; ++nt)
        acc[mt][nt] = __builtin_amdgcn_mfma_f32_16x16x32_bf16(a[mt], b[nt],
                                                              acc[mt][nt], 0, 0, 0);
    __syncthreads();
  }

  // epilogue: C/D layout col=lane&15, row=(lane>>4)*4+reg  [m89-verified]
#pragma unroll
  for (int nt = 0; nt < 4; ++nt) {
    int col = bcol + wc * 64 + nt * 16 + lr;
    float bs = bias[col];
#pragma unroll
    for (int mt = 0; mt < 4; ++mt) {
#pragma unroll
      for (int i = 0; i < 4; ++i) {
        int row = brow + wr * 64 + mt * 16 + lg * 4 + i;
        float v = acc[mt][nt][i] + bs;
        if (EPI == 1) v = tanhf(v);
        else v = fmaxf(v, 0.0f);
        if (EPI == 2) Cf[(size_t)row * N + col] = v;
        else Cb[(size_t)row * N + col] = f2bf(v);
      }
    }
  }
}

// ---------------- launch ----------------

extern "C" void kernel_launch(void* const* d_in, const int* in_sizes, int n_in,
                              void* d_out, int out_size, void* d_ws,
                              size_t ws_size, hipStream_t stream) {
  const float* x     = (const float*)d_in[0];
  const float* w0    = (const float*)d_in[1];
  const float* b0    = (const float*)d_in[2];
  const float* w1    = (const float*)d_in[3];
  const float* b1    = (const float*)d_in[4];
  const float* infw1 = (const float*)d_in[5];
  const float* clsw1 = (const float*)d_in[6];
  const float* clsb1 = (const float*)d_in[7];
  const float* w2    = (const float*)d_in[8];
  const float* b2    = (const float*)d_in[9];
  const float* infw2 = (const float*)d_in[10];
  const float* clsw2 = (const float*)d_in[11];
  const float* clsb2 = (const float*)d_in[12];
  const float* w3    = (const float*)d_in[13];
  const float* b3    = (const float*)d_in[14];
  float* out = (float*)d_out;

  char* ws = (char*)d_ws;
  const size_t MB = 1ull << 20;
  const size_t DDe = (size_t)DD * DD;
  unsigned short* buf0 = (unsigned short*)ws;              // 8 MB (x_bf16 / act)
  unsigned short* buf1 = (unsigned short*)(ws + 8 * MB);   // 8 MB (act)
  unsigned short* wts  = (unsigned short*)(ws + 16 * MB);  // 6 x 8 MB
  float* padd1 = (float*)(ws + 64 * MB);
  float* padd2 = padd1 + DD;

  dim3 tb(32, 8), tg(DD / 32, DD / 32);
  transpose_cvt_kernel<<<tg, tb, 0, stream>>>(w0,    wts + 0 * DDe);
  transpose_cvt_kernel<<<tg, tb, 0, stream>>>(w1,    wts + 1 * DDe);
  transpose_cvt_kernel<<<tg, tb, 0, stream>>>(clsw1, wts + 2 * DDe);
  transpose_cvt_kernel<<<tg, tb, 0, stream>>>(w2,    wts + 3 * DDe);
  transpose_cvt_kernel<<<tg, tb, 0, stream>>>(clsw2, wts + 4 * DDe);
  transpose_cvt_kernel<<<tg, tb, 0, stream>>>(w3,    wts + 5 * DDe);

  cvt_bf16_kernel<<<(int)(DDe / 4 / 256), 256, 0, stream>>>(x, buf0, (int)(DDe / 4));
  padd_kernel<<<DD / 256, 256, 0, stream>>>(infw1, clsb1, padd1);
  padd_kernel<<<DD / 256, 256, 0, stream>>>(infw2, clsb2, padd2);

  dim3 gg((DD / BM) * (DD / BN));  // 256 blocks, swizzled inside
  gemm_kernel<0><<<gg, 256, 0, stream>>>(buf0, wts + 0 * DDe, b0,    buf1, nullptr);
  gemm_kernel<0><<<gg, 256, 0, stream>>>(buf1, wts + 1 * DDe, b1,    buf0, nullptr);
  gemm_kernel<1><<<gg, 256, 0, stream>>>(buf0, wts + 2 * DDe, padd1, buf1, nullptr);
  gemm_kernel<0><<<gg, 256, 0, stream>>>(buf1, wts + 3 * DDe, b2,    buf0, nullptr);
  gemm_kernel<1><<<gg, 256, 0, stream>>>(buf0, wts + 4 * DDe, padd2, buf1, nullptr);
  gemm_kernel<2><<<gg, 256, 0, stream>>>(buf1, wts + 5 * DDe, b3,    nullptr, out);
}

// Round 2
// 265.033 us; speedup vs baseline: 1.1725x; 1.1725x over previous
//
#include <hip/hip_runtime.h>
#include <hip/hip_bf16.h>

// InfiniteNeuralNetwork: the scan state stays row-constant, so
//   p[j] = (1/D) * prod_{d,k} cos^2(inf_w[d,j,k])
// and each infinite layer is just tanh(x @ cls_w + cls_b + p).
// Network = 6 GEMMs [2048x2048x2048] with fused epilogues.
// R1: BN 128->64 (512 blocks = 2 blocks/CU at N=2048) + fused prep launches.

#define DD 2048
#define DEPTH 9

#define BM 128
#define BN 64
#define BK 32

typedef __attribute__((ext_vector_type(8))) short short8;
typedef __attribute__((ext_vector_type(4))) float f32x4;

__device__ __forceinline__ unsigned short f2bf(float f) {
  unsigned u = __float_as_uint(f);
  u += 0x7FFFu + ((u >> 16) & 1u);   // round-to-nearest-even
  return (unsigned short)(u >> 16);
}

// ---------------- prep kernels ----------------

__global__ void cvt_bf16_kernel(const float* __restrict__ s,
                                unsigned short* __restrict__ d, int n4) {
  int i = blockIdx.x * 256 + threadIdx.x;
  if (i >= n4) return;
  float4 v = reinterpret_cast<const float4*>(s)[i];
  ushort4 o;
  o.x = f2bf(v.x); o.y = f2bf(v.y); o.z = f2bf(v.z); o.w = f2bf(v.w);
  reinterpret_cast<ushort4*>(d)[i] = o;
}

// dst[z][n*D + k] = bf16(src_z[k*D + n])  for 6 weights in one launch
__global__ void transpose6_kernel(const float* __restrict__ s0,
                                  const float* __restrict__ s1,
                                  const float* __restrict__ s2,
                                  const float* __restrict__ s3,
                                  const float* __restrict__ s4,
                                  const float* __restrict__ s5,
                                  unsigned short* __restrict__ wts) {
  __shared__ float tile[32][33];
  const float* src;
  switch (blockIdx.z) {
    case 0: src = s0; break;
    case 1: src = s1; break;
    case 2: src = s2; break;
    case 3: src = s3; break;
    case 4: src = s4; break;
    default: src = s5; break;
  }
  unsigned short* dst = wts + (size_t)blockIdx.z * DD * DD;
  int bx = blockIdx.x * 32;  // n base
  int by = blockIdx.y * 32;  // k base
  int tx = threadIdx.x, ty = threadIdx.y;
#pragma unroll
  for (int i = ty; i < 32; i += 8)
    tile[i][tx] = src[(size_t)(by + i) * DD + bx + tx];
  __syncthreads();
#pragma unroll
  for (int i = ty; i < 32; i += 8)
    dst[(size_t)(bx + i) * DD + by + tx] = f2bf(tile[tx][i]);
}

// padd[j] = cls_b[j] + (1/D) * prod_{d,k} cos^2(inf_w[d,j,k])  (both layers)
__global__ void padd_kernel(const float* __restrict__ infw1,
                            const float* __restrict__ infw2,
                            const float* __restrict__ clsb1,
                            const float* __restrict__ clsb2,
                            float* __restrict__ padd1,
                            float* __restrict__ padd2) {
  int j = blockIdx.x * 256 + threadIdx.x;
  if (j >= DD) return;
  const float* inf_w = blockIdx.y ? infw2 : infw1;
  const float* cls_b = blockIdx.y ? clsb2 : clsb1;
  float* padd = blockIdx.y ? padd2 : padd1;
  float prod = 1.0f;
#pragma unroll
  for (int d = 0; d < DEPTH; ++d) {
    const float* row = inf_w + ((size_t)d * DD + j) * DD;
    prod *= cosf(row[0]) * cosf(row[1]) * cosf(row[2]);
  }
  padd[j] = cls_b[j] + prod * prod * (1.0f / (float)DD);
}

// ---------------- GEMM ----------------

__device__ __forceinline__ void gload_lds16(const unsigned short* g,
                                            unsigned short* l) {
  __builtin_amdgcn_global_load_lds(
      (const __attribute__((address_space(1))) void*)g,
      (__attribute__((address_space(3))) void*)l, 16, 0, 0);
}

// EPI: 0 = relu -> bf16, 1 = tanh -> bf16, 2 = relu -> f32
// A: [M][K] bf16 row-major. Bt: [N][K] bf16 (transposed weight). bias: [N] f32.
template <int EPI>
__global__ __launch_bounds__(256) void gemm_kernel(
    const unsigned short* __restrict__ A, const unsigned short* __restrict__ Bt,
    const float* __restrict__ bias, unsigned short* __restrict__ Cb,
    float* __restrict__ Cf) {
  const int N = DD, K = DD;
  __shared__ unsigned short As[BM * BK];  // [128][32]
  __shared__ unsigned short Bs[BN * BK];  // [64][32]

  int tid = threadIdx.x;
  int wid = tid >> 6, lane = tid & 63;
  int wr = wid >> 1, wc = wid & 1;   // wave grid 2x2; wave owns 64M x 32N
  int lr = lane & 15;
  int lg = lane >> 4;
  int lk = lg * 8;

  // XCD-aware bijective swizzle over 512 blocks (512 % 8 == 0).
  int bid = blockIdx.x;
  int swz = (bid & 7) * 64 + (bid >> 3);
  int bcol = (swz & 31) * BN;   // 32 n-tiles
  int brow = (swz >> 5) * BM;   // 16 m-tiles

  f32x4 acc[4][2];
#pragma unroll
  for (int i = 0; i < 4; ++i)
#pragma unroll
    for (int j = 0; j < 2; ++j) acc[i][j] = f32x4{0.f, 0.f, 0.f, 0.f};

  for (int kt = 0; kt < K; kt += BK) {
    // A tile: 128x32 bf16 = 512 x 16B chunks, 2 passes of 256 threads
#pragma unroll
    for (int r = 0; r < 2; ++r) {
      int chunk = r * 256 + tid;
      int row = chunk >> 2;               // 4 chunks per 64B row
      int kof = (chunk & 3) * 8;
      gload_lds16(A + (size_t)(brow + row) * K + kt + kof,
                  &As[(size_t)(r * 256 + wid * 64) * 8]);
    }
    // B tile: 64x32 bf16 = 256 x 16B chunks, 1 pass
    {
      int row = tid >> 2;
      int kof = (tid & 3) * 8;
      gload_lds16(Bt + (size_t)(bcol + row) * K + kt + kof,
                  &Bs[(size_t)(wid * 64) * 8]);
    }
    __syncthreads();

    short8 a[4], b[2];
#pragma unroll
    for (int mt = 0; mt < 4; ++mt)
      a[mt] = *reinterpret_cast<const short8*>(
          &As[(wr * 64 + mt * 16 + lr) * BK + lk]);
#pragma unroll
    for (int nt = 0; nt < 2; ++nt)
      b[nt] = *reinterpret_cast<const short8*>(
          &Bs[(wc * 32 + nt * 16 + lr) * BK + lk]);
#pragma unroll
    for (int mt = 0; mt < 4; ++mt)
#pragma unroll
      for (int nt = 0; nt < 2; ++nt)
        acc[mt][nt] = __builtin_amdgcn_mfma_f32_16x16x32_bf16(a[mt], b[nt],
                                                              acc[mt][nt], 0, 0, 0);
    __syncthreads();
  }

  // epilogue: C/D layout col=lane&15, row=(lane>>4)*4+reg  [m89-verified]
#pragma unroll
  for (int nt = 0; nt < 2; ++nt) {
    int col = bcol + wc * 32 + nt * 16 + lr;
    float bs = bias[col];
#pragma unroll
    for (int mt = 0; mt < 4; ++mt) {
#pragma unroll
      for (int i = 0; i < 4; ++i) {
        int row = brow + wr * 64 + mt * 16 + lg * 4 + i;
        float v = acc[mt][nt][i] + bs;
        if (EPI == 1) v = tanhf(v);
        else v = fmaxf(v, 0.0f);
        if (EPI == 2) Cf[(size_t)row * N + col] = v;
        else Cb[(size_t)row * N + col] = f2bf(v);
      }
    }
  }
}

// ---------------- launch ----------------

extern "C" void kernel_launch(void* const* d_in, const int* in_sizes, int n_in,
                              void* d_out, int out_size, void* d_ws,
                              size_t ws_size, hipStream_t stream) {
  const float* x     = (const float*)d_in[0];
  const float* w0    = (const float*)d_in[1];
  const float* b0    = (const float*)d_in[2];
  const float* w1    = (const float*)d_in[3];
  const float* b1    = (const float*)d_in[4];
  const float* infw1 = (const float*)d_in[5];
  const float* clsw1 = (const float*)d_in[6];
  const float* clsb1 = (const float*)d_in[7];
  const float* w2    = (const float*)d_in[8];
  const float* b2    = (const float*)d_in[9];
  const float* infw2 = (const float*)d_in[10];
  const float* clsw2 = (const float*)d_in[11];
  const float* clsb2 = (const float*)d_in[12];
  const float* w3    = (const float*)d_in[13];
  const float* b3    = (const float*)d_in[14];
  float* out = (float*)d_out;

  char* ws = (char*)d_ws;
  const size_t MB = 1ull << 20;
  const size_t DDe = (size_t)DD * DD;
  unsigned short* buf0 = (unsigned short*)ws;              // 8 MB (x_bf16 / act)
  unsigned short* buf1 = (unsigned short*)(ws + 8 * MB);   // 8 MB (act)
  unsigned short* wts  = (unsigned short*)(ws + 16 * MB);  // 6 x 8 MB
  float* padd1 = (float*)(ws + 64 * MB);
  float* padd2 = padd1 + DD;

  transpose6_kernel<<<dim3(DD / 32, DD / 32, 6), dim3(32, 8), 0, stream>>>(
      w0, w1, clsw1, w2, clsw2, w3, wts);
  cvt_bf16_kernel<<<(int)(DDe / 4 / 256), 256, 0, stream>>>(x, buf0,
                                                            (int)(DDe / 4));
  padd_kernel<<<dim3(DD / 256, 2), 256, 0, stream>>>(infw1, infw2, clsb1,
                                                     clsb2, padd1, padd2);

  dim3 gg((DD / BM) * (DD / BN));  // 512 blocks -> 2 blocks/CU
  gemm_kernel<0><<<gg, 256, 0, stream>>>(buf0, wts + 0 * DDe, b0,    buf1, nullptr);
  gemm_kernel<0><<<gg, 256, 0, stream>>>(buf1, wts + 1 * DDe, b1,    buf0, nullptr);
  gemm_kernel<1><<<gg, 256, 0, stream>>>(buf0, wts + 2 * DDe, padd1, buf1, nullptr);
  gemm_kernel<0><<<gg, 256, 0, stream>>>(buf1, wts + 3 * DDe, b2,    buf0, nullptr);
  gemm_kernel<1><<<gg, 256, 0, stream>>>(buf0, wts + 4 * DDe, padd2, buf1, nullptr);
  gemm_kernel<2><<<gg, 256, 0, stream>>>(buf1, wts + 5 * DDe, b3,    nullptr, out);
}